// Round 18
// baseline (238.024 us; speedup 1.0000x reference)
//
#include <hip/hip_runtime.h>
#include <hip/hip_bf16.h>
#include <hip/hip_fp16.h>

#define IN_DIM 4096
#define OUT_DIM 4096
#define HAD_SCALE_F 0.08838834764831845f   // 2^-3.5

typedef int   i32x4 __attribute__((ext_vector_type(4)));
typedef float f32x4 __attribute__((ext_vector_type(4)));

// ---------------------------------------------------------------------------
// Kernel A (verified R12/R13): wave/in-register FWHT, 16 elems/thread,
// s_a = rowmax/127, rowsum = s_a*sum(q) (self-consistent decomposition).
// ---------------------------------------------------------------------------
__global__ __launch_bounds__(256)
void had_rows_q(const float* __restrict__ x, int* __restrict__ aq,
                float* __restrict__ rowsum, float* __restrict__ srow)
{
    __shared__ float wmx[4];
    __shared__ int   wqs[4];
    const int tid = threadIdx.x;
    const int wv  = tid >> 6;
    const size_t row = blockIdx.x;
    const float* xr = x + row * IN_DIM + tid * 16;

    float e[16];
    #pragma unroll
    for (int v = 0; v < 4; ++v) {
        const float4 f = ((const float4*)xr)[v];
        e[v*4+0] = f.x; e[v*4+1] = f.y; e[v*4+2] = f.z; e[v*4+3] = f.w;
    }

    #pragma unroll
    for (int s = 1; s < 16; s <<= 1) {
        #pragma unroll
        for (int i = 0; i < 16; ++i) {
            if (!(i & s)) {
                const float u = e[i], w2 = e[i | s];
                e[i]     = u + w2;
                e[i | s] = u - w2;
            }
        }
    }
    #pragma unroll
    for (int m = 1; m <= 4; m <<= 1) {
        const float sgn = (tid & m) ? -1.0f : 1.0f;
        #pragma unroll
        for (int i = 0; i < 16; ++i) {
            const float p = __shfl_xor(e[i], m, 64);
            e[i] = fmaf(sgn, e[i], p);
        }
    }

    float smax = 0.f;
    #pragma unroll
    for (int i = 0; i < 16; ++i) {
        e[i] *= HAD_SCALE_F;
        smax = fmaxf(smax, fabsf(e[i]));
    }
    #pragma unroll
    for (int off = 32; off > 0; off >>= 1)
        smax = fmaxf(smax, __shfl_xor(smax, off, 64));
    if ((tid & 63) == 0) wmx[wv] = smax;
    __syncthreads();
    const float mx  = fmaxf(fmaxf(wmx[0], wmx[1]), fmaxf(wmx[2], wmx[3]));
    const float inv = (mx > 0.f) ? 127.0f / mx : 0.f;
    const float sa  = mx * (1.0f / 127.0f);

    int qsum = 0;
    int pk[4];
    #pragma unroll
    for (int g2 = 0; g2 < 4; ++g2) {
        const int q0 = (int)rintf(e[g2*4+0] * inv);
        const int q1 = (int)rintf(e[g2*4+1] * inv);
        const int q2 = (int)rintf(e[g2*4+2] * inv);
        const int q3 = (int)rintf(e[g2*4+3] * inv);
        qsum += (q0 + q1) + (q2 + q3);
        pk[g2] = (q0 & 0xFF) | ((q1 & 0xFF) << 8) | ((q2 & 0xFF) << 16) | (q3 << 24);
    }
    *(int4*)&aq[row * (IN_DIM / 4) + tid * 4] = make_int4(pk[0], pk[1], pk[2], pk[3]);

    #pragma unroll
    for (int off = 32; off > 0; off >>= 1) qsum += __shfl_xor(qsum, off, 64);
    if ((tid & 63) == 0) wqs[wv] = qsum;
    __syncthreads();
    if (tid == 0) {
        rowsum[row] = sa * (float)((wqs[0] + wqs[1]) + (wqs[2] + wqs[3]));
        srow[row]   = sa;
    }
}

// ---------------------------------------------------------------------------
// Kernel B (verified R15): repack int4 weights into interleaved-nibble chunks.
// packed & 0x0F0F0F0F = kb0 fragment, (packed>>4) & 0x0F0F0F0F = kb1.
// ---------------------------------------------------------------------------
__global__ __launch_bounds__(256)
void unpack_w4i(const int* __restrict__ wp, unsigned char* __restrict__ wf4)
{
    const int gid = blockIdx.x * 256 + threadIdx.x;   // 4096*32*4 = 524288
    const int c   = gid & 3;
    const int kt  = (gid >> 2) & 31;
    const int n   = gid >> 7;
    const int kbase = kt * 128 + c * 16;
    const int* row = wp + (size_t)n * (IN_DIM / 2) + (kbase >> 1);
    const int4 plo0 = *(const int4*)(row);
    const int4 plo1 = *(const int4*)(row + 4);
    const int4 phi0 = *(const int4*)(row + 32);
    const int4 phi1 = *(const int4*)(row + 36);

    #define MKD(lo, hi, lo2, hi2) \
        ( (unsigned)(((lo) & 15) | (((hi) & 15) << 4)) \
        | ((unsigned)((((lo) >> 4) & 15) | ((((hi) >> 4) & 15) << 4)) << 8) \
        | ((unsigned)(((lo2) & 15) | (((hi2) & 15) << 4)) << 16) \
        | ((unsigned)((((lo2) >> 4) & 15) | ((((hi2) >> 4) & 15) << 4)) << 24) )

    uint4 o;
    o.x = MKD(plo0.x, phi0.x, plo0.y, phi0.y);
    o.y = MKD(plo0.z, phi0.z, plo0.w, phi0.w);
    o.z = MKD(plo1.x, phi1.x, plo1.y, phi1.y);
    o.w = MKD(plo1.z, phi1.z, plo1.w, phi1.w);
    #undef MKD
    *(uint4*)(wf4 + (size_t)gid * 16) = o;
}

// ---------------------------------------------------------------------------
// Kernel C (round-17, compile-fixed): 256x256 block, 4 waves in a 2x2 grid —
// wave tile 128x128, acc = 256 AGPRs/wave at 1 wave/SIMD (512 unified regs,
// launch_bounds(256,1)). Attacks the additive law's LDS TERM via read
// amplification: per wave per K-128 region A = 16 b128 (its 128 rows),
// B = 8 packed b128 (its 128 cols, both kb per read) -> 96 b128/CU-region
// vs R15's 160 (-40%), writes 48KB vs 64KB. MFMA term unchanged.
// LDS 80KB: A dbuf 2x32KB + packed-int4 B 16KB. All staging/swizzle/
// barrier discipline verbatim from verified R15 (A-stage now 8 rounds).
// ---------------------------------------------------------------------------
#define NT 32   // K-regions of 128

#define BAR()        asm volatile("s_barrier" ::: "memory")
#define WAIT_VM(N)   asm volatile("s_waitcnt vmcnt(" #N ")" ::: "memory")
#define WAIT_LGKM0() asm volatile("s_waitcnt lgkmcnt(0)" ::: "memory")

// LDS: A0 @ 0 (32K), A1 @ 32768 (32K), B @ 65536 (16K)
#define STAGE_A(buf, kt) do { \
    _Pragma("unroll") for (int R = 0; R < 8; ++R) \
        __builtin_amdgcn_global_load_lds( \
            (const __attribute__((address_space(1))) void*)(sA + ((size_t)R << 17) + (((kt) & 31) << 7)), \
            (__attribute__((address_space(3))) void*)(smem + (buf) * 32768 + R * 4096 + wv * 1024), 16, 0, 0); \
    } while (0)
#define STAGE_B(kt) do { \
    _Pragma("unroll") for (int R = 0; R < 4; ++R) \
        __builtin_amdgcn_global_load_lds( \
            (const __attribute__((address_space(1))) void*)(sB + ((size_t)R << 17) + (((kt) & 31) << 6)), \
            (__attribute__((address_space(3))) void*)(smem + 65536 + R * 4096 + wv * 1024), 16, 0, 0); \
    } while (0)

__global__ __launch_bounds__(256, 1)
void gemm_i8(const signed char* __restrict__ Aq, const unsigned char* __restrict__ Bw4,
             const float* __restrict__ wscale, const float* __restrict__ wadd,
             const float* __restrict__ bias, const float* __restrict__ rowsum,
             const float* __restrict__ srow, float* __restrict__ out)
{
    __shared__ char smem[81920];

    const int tid  = threadIdx.x;
    const int lane = tid & 63;
    const int wv   = tid >> 6;    // wave 0..3
    const int wm   = wv >> 1;     // 2x2 wave grid
    const int wn   = wv & 1;

    // XCD swizzle: 512 wgs = 8 XCDs x 64
    const int bid = blockIdx.x;
    const int wg  = (bid & 7) * 64 + (bid >> 3);
    const int m0  = (wg >> 4) * 256;   // 32 m-tiles
    const int n0  = (wg & 15) * 256;   // 16 n-tiles

    // ---- A staging (verified pattern, 8 rounds of 32 rows) ----
    const int art = tid >> 3;
    const int act = (tid & 7) ^ (art & 7);
    const signed char* sA = Aq + (size_t)(m0 + art) * IN_DIM + act * 16;

    // ---- B staging (verified pattern, 4 rounds of 64 rows, 64B rows) ----
    const int brt = tid >> 2;
    const int bct = (tid & 3) ^ (brt & 3);
    const unsigned char* sB = Bw4 + (size_t)(n0 + brt) * 2048 + bct * 16;

    // ---- fragment read offsets ----
    const int l15 = lane & 15, g = lane >> 4, l7 = lane & 7, l3 = lane & 3;
    const int aOff = wm * 16384 + l15 * 128 + ((g ^ l7) << 4);   // + mi*2048, ^64 kb1
    const int bOff = 65536 + (wn * 128 + l15) * 64 + ((g ^ l3) << 4);  // + ni*1024

    i32x4 afr[4][2], b0[8], b1[8];
    i32x4 acc[8][8] = {};   // [mi 0..7][ni 0..7]

    // ---- prologue ----
    STAGE_A(0, 0);
    STAGE_B(0);
    WAIT_VM(0);
    BAR();

    #pragma unroll 1
    for (int kt = 0; kt < NT; ++kt) {
        const int cur = kt & 1;

        STAGE_A(cur ^ 1, kt + 1);

        // read B packed (8 b128) + A rows h0 (8 b128)
        i32x4 bp[8];
        #pragma unroll
        for (int ni = 0; ni < 8; ++ni)
            bp[ni] = *(const i32x4*)(smem + bOff + ni * 1024);
        #pragma unroll
        for (int mi = 0; mi < 4; ++mi) {
            afr[mi][0] = *(const i32x4*)(smem + cur * 32768 + mi * 2048 + aOff);
            afr[mi][1] = *(const i32x4*)(smem + cur * 32768 + mi * 2048 + (aOff ^ 64));
        }
        #pragma unroll
        for (int ni = 0; ni < 8; ++ni) {
            #pragma unroll
            for (int d = 0; d < 4; ++d) {
                b0[ni][d] = bp[ni][d] & 0x0F0F0F0F;
                b1[ni][d] = (int)(((unsigned)bp[ni][d] >> 4) & 0x0F0F0F0F);
            }
        }

        WAIT_LGKM0();       // all own B reads complete before barrier
        BAR();              // all waves done reading B -> safe to restage
        STAGE_B(kt + 1);    // lands under the MFMA bursts below

        __builtin_amdgcn_s_setprio(1);
        #pragma unroll
        for (int mi = 0; mi < 4; ++mi)
            #pragma unroll
            for (int ni = 0; ni < 8; ++ni)
                acc[mi][ni] = __builtin_amdgcn_mfma_i32_16x16x64_i8(
                    afr[mi][0], b0[ni], acc[mi][ni], 0, 0, 0);
        #pragma unroll
        for (int mi = 0; mi < 4; ++mi)
            #pragma unroll
            for (int ni = 0; ni < 8; ++ni)
                acc[mi][ni] = __builtin_amdgcn_mfma_i32_16x16x64_i8(
                    afr[mi][1], b1[ni], acc[mi][ni], 0, 0, 0);
        __builtin_amdgcn_s_setprio(0);

        // read A rows h1 and finish
        #pragma unroll
        for (int mi = 0; mi < 4; ++mi) {
            afr[mi][0] = *(const i32x4*)(smem + cur * 32768 + (mi + 4) * 2048 + aOff);
            afr[mi][1] = *(const i32x4*)(smem + cur * 32768 + (mi + 4) * 2048 + (aOff ^ 64));
        }
        __builtin_amdgcn_s_setprio(1);
        #pragma unroll
        for (int mi = 0; mi < 4; ++mi)
            #pragma unroll
            for (int ni = 0; ni < 8; ++ni)
                acc[mi + 4][ni] = __builtin_amdgcn_mfma_i32_16x16x64_i8(
                    afr[mi][0], b0[ni], acc[mi + 4][ni], 0, 0, 0);
        #pragma unroll
        for (int mi = 0; mi < 4; ++mi)
            #pragma unroll
            for (int ni = 0; ni < 8; ++ni)
                acc[mi + 4][ni] = __builtin_amdgcn_mfma_i32_16x16x64_i8(
                    afr[mi][1], b1[ni], acc[mi + 4][ni], 0, 0, 0);
        __builtin_amdgcn_s_setprio(0);

        WAIT_VM(0);         // A(kt+1)+B(kt+1) landed (issued a burst ago)
        BAR();
    }

    // ---- epilogue: y = srow[m]*wscale[n]*acc + wadd[n]*rowsum[m] + bias[n] ----
    #pragma unroll
    for (int ni = 0; ni < 8; ++ni) {
        const int col = n0 + wn * 128 + ni * 16 + l15;
        const float sc = wscale[col];
        const float ad = wadd[col];
        const float bi = bias[col];
        #pragma unroll
        for (int mi = 0; mi < 8; ++mi) {
            const int row = m0 + wm * 128 + mi * 16 + g * 4;
            const float4 rs4 = *(const float4*)&rowsum[row];
            const float4 sr4 = *(const float4*)&srow[row];
            #pragma unroll
            for (int j = 0; j < 4; ++j) {
                const float rs = (j == 0) ? rs4.x : (j == 1) ? rs4.y : (j == 2) ? rs4.z : rs4.w;
                const float sr = (j == 0) ? sr4.x : (j == 1) ? sr4.y : (j == 2) ? sr4.z : sr4.w;
                out[(size_t)(row + j) * OUT_DIM + col] =
                    (float)acc[mi][ni][j] * (sc * sr) + ad * rs + bi;
            }
        }
    }
}

// ---------------------------------------------------------------------------
extern "C" void kernel_launch(void* const* d_in, const int* in_sizes, int n_in,
                              void* d_out, int out_size, void* d_ws, size_t ws_size,
                              hipStream_t stream)
{
    const float* x      = (const float*)d_in[0];
    const int*   wp     = (const int*)d_in[1];
    const float* wscale = (const float*)d_in[2];
    const float* wadd   = (const float*)d_in[3];
    const float* bias   = (const float*)d_in[4];
    float*       out    = (float*)d_out;

    const int M = in_sizes[0] / IN_DIM;   // 8192

    // ws layout: [ wf4 i4 N*K/2 (8MB) | aq i8 M*K | rowsum f32 M | srow f32 M ]
    char* ws = (char*)d_ws;
    unsigned char* wf4 = (unsigned char*)ws;
    const size_t wf_bytes = (size_t)OUT_DIM * IN_DIM / 2;
    int* aq = (int*)(ws + wf_bytes);
    const size_t aq_bytes = (size_t)M * IN_DIM;
    float* rowsum = (float*)(ws + wf_bytes + aq_bytes);
    float* srow   = (float*)(ws + wf_bytes + aq_bytes + (size_t)M * 4);

    unpack_w4i<<<(OUT_DIM * 32 * 4) / 256, 256, 0, stream>>>(wp, wf4);

    had_rows_q<<<M, 256, 0, stream>>>(x, aq, rowsum, srow);

    gemm_i8<<<(M / 256) * (OUT_DIM / 256), 256, 0, stream>>>(
        (const signed char*)aq, wf4, wscale, wadd, bias, rowsum, srow, out);
}

// Round 19
// 174.844 us; speedup vs baseline: 1.3614x; 1.3614x over previous
//
#include <hip/hip_runtime.h>
#include <hip/hip_bf16.h>
#include <hip/hip_fp16.h>

#define IN_DIM 4096
#define OUT_DIM 4096
#define HAD_SCALE_F 0.08838834764831845f   // 2^-3.5

typedef int   i32x4 __attribute__((ext_vector_type(4)));
typedef float f32x4 __attribute__((ext_vector_type(4)));

// ---------------------------------------------------------------------------
// Kernel A (verified R12/R13/R15): wave/in-register FWHT, 16 elems/thread,
// s_a = rowmax/127, rowsum = s_a*sum(q) (self-consistent decomposition).
// ---------------------------------------------------------------------------
__global__ __launch_bounds__(256)
void had_rows_q(const float* __restrict__ x, int* __restrict__ aq,
                float* __restrict__ rowsum, float* __restrict__ srow)
{
    __shared__ float wmx[4];
    __shared__ int   wqs[4];
    const int tid = threadIdx.x;
    const int wv  = tid >> 6;
    const size_t row = blockIdx.x;
    const float* xr = x + row * IN_DIM + tid * 16;

    float e[16];
    #pragma unroll
    for (int v = 0; v < 4; ++v) {
        const float4 f = ((const float4*)xr)[v];
        e[v*4+0] = f.x; e[v*4+1] = f.y; e[v*4+2] = f.z; e[v*4+3] = f.w;
    }

    #pragma unroll
    for (int s = 1; s < 16; s <<= 1) {
        #pragma unroll
        for (int i = 0; i < 16; ++i) {
            if (!(i & s)) {
                const float u = e[i], w2 = e[i | s];
                e[i]     = u + w2;
                e[i | s] = u - w2;
            }
        }
    }
    #pragma unroll
    for (int m = 1; m <= 4; m <<= 1) {
        const float sgn = (tid & m) ? -1.0f : 1.0f;
        #pragma unroll
        for (int i = 0; i < 16; ++i) {
            const float p = __shfl_xor(e[i], m, 64);
            e[i] = fmaf(sgn, e[i], p);
        }
    }

    float smax = 0.f;
    #pragma unroll
    for (int i = 0; i < 16; ++i) {
        e[i] *= HAD_SCALE_F;
        smax = fmaxf(smax, fabsf(e[i]));
    }
    #pragma unroll
    for (int off = 32; off > 0; off >>= 1)
        smax = fmaxf(smax, __shfl_xor(smax, off, 64));
    if ((tid & 63) == 0) wmx[wv] = smax;
    __syncthreads();
    const float mx  = fmaxf(fmaxf(wmx[0], wmx[1]), fmaxf(wmx[2], wmx[3]));
    const float inv = (mx > 0.f) ? 127.0f / mx : 0.f;
    const float sa  = mx * (1.0f / 127.0f);

    int qsum = 0;
    int pk[4];
    #pragma unroll
    for (int g2 = 0; g2 < 4; ++g2) {
        const int q0 = (int)rintf(e[g2*4+0] * inv);
        const int q1 = (int)rintf(e[g2*4+1] * inv);
        const int q2 = (int)rintf(e[g2*4+2] * inv);
        const int q3 = (int)rintf(e[g2*4+3] * inv);
        qsum += (q0 + q1) + (q2 + q3);
        pk[g2] = (q0 & 0xFF) | ((q1 & 0xFF) << 8) | ((q2 & 0xFF) << 16) | (q3 << 24);
    }
    *(int4*)&aq[row * (IN_DIM / 4) + tid * 4] = make_int4(pk[0], pk[1], pk[2], pk[3]);

    #pragma unroll
    for (int off = 32; off > 0; off >>= 1) qsum += __shfl_xor(qsum, off, 64);
    if ((tid & 63) == 0) wqs[wv] = qsum;
    __syncthreads();
    if (tid == 0) {
        rowsum[row] = sa * (float)((wqs[0] + wqs[1]) + (wqs[2] + wqs[3]));
        srow[row]   = sa;
    }
}

// ---------------------------------------------------------------------------
// Kernel B (verified R15): repack int4 weights into interleaved-nibble chunks.
// packed & 0x0F0F0F0F = kb0 fragment, (packed>>4) & 0x0F0F0F0F = kb1.
// ---------------------------------------------------------------------------
__global__ __launch_bounds__(256)
void unpack_w4i(const int* __restrict__ wp, unsigned char* __restrict__ wf4)
{
    const int gid = blockIdx.x * 256 + threadIdx.x;   // 4096*32*4 = 524288
    const int c   = gid & 3;
    const int kt  = (gid >> 2) & 31;
    const int n   = gid >> 7;
    const int kbase = kt * 128 + c * 16;
    const int* row = wp + (size_t)n * (IN_DIM / 2) + (kbase >> 1);
    const int4 plo0 = *(const int4*)(row);
    const int4 plo1 = *(const int4*)(row + 4);
    const int4 phi0 = *(const int4*)(row + 32);
    const int4 phi1 = *(const int4*)(row + 36);

    #define MKD(lo, hi, lo2, hi2) \
        ( (unsigned)(((lo) & 15) | (((hi) & 15) << 4)) \
        | ((unsigned)((((lo) >> 4) & 15) | ((((hi) >> 4) & 15) << 4)) << 8) \
        | ((unsigned)(((lo2) & 15) | (((hi2) & 15) << 4)) << 16) \
        | ((unsigned)((((lo2) >> 4) & 15) | ((((hi2) >> 4) & 15) << 4)) << 24) )

    uint4 o;
    o.x = MKD(plo0.x, phi0.x, plo0.y, phi0.y);
    o.y = MKD(plo0.z, phi0.z, plo0.w, phi0.w);
    o.z = MKD(plo1.x, phi1.x, plo1.y, phi1.y);
    o.w = MKD(plo1.z, phi1.z, plo1.w, phi1.w);
    #undef MKD
    *(uint4*)(wf4 + (size_t)gid * 16) = o;
}

// ---------------------------------------------------------------------------
// Kernel C — R15 VERBATIM (best verified GEMM: 135.7 us, MfmaUtil 45%,
// 2 co-resident blocks/CU). 128x256 block, 4 waves (wave tile 128x64),
// LDS 48 KiB: A i8 dbuf 2x16K (XOR swizzle) + packed-int4 B 16K (in-register
// nibble unpack, 2 VALU/dword). R17/18's 128x128 wave tile (1 wave/SIMD)
// regressed to 206 us: VGPR cap 256 -> spill + zero TLP exposed ds_read
// latency. Restored. Region: {STAGE_A(kt+1); read B+A_h0; lgkm(0); BAR;
// STAGE_B(kt+1); MFMA h0; read A_h1; MFMA h1; vmcnt(0); BAR}.
// ---------------------------------------------------------------------------
#define NT 32   // K-regions of 128

#define BAR()        asm volatile("s_barrier" ::: "memory")
#define WAIT_VM(N)   asm volatile("s_waitcnt vmcnt(" #N ")" ::: "memory")
#define WAIT_LGKM0() asm volatile("s_waitcnt lgkmcnt(0)" ::: "memory")

// LDS: A0 @ 0 (16K), A1 @ 16384, B @ 32768 (16K)
#define STAGE_A(buf, kt) do { \
    _Pragma("unroll") for (int R = 0; R < 4; ++R) \
        __builtin_amdgcn_global_load_lds( \
            (const __attribute__((address_space(1))) void*)(sA + ((size_t)R << 17) + (((kt) & 31) << 7)), \
            (__attribute__((address_space(3))) void*)(smem + (buf) * 16384 + R * 4096 + wv * 1024), 16, 0, 0); \
    } while (0)
#define STAGE_B(kt) do { \
    _Pragma("unroll") for (int R = 0; R < 4; ++R) \
        __builtin_amdgcn_global_load_lds( \
            (const __attribute__((address_space(1))) void*)(sB + ((size_t)R << 17) + (((kt) & 31) << 6)), \
            (__attribute__((address_space(3))) void*)(smem + 32768 + R * 4096 + wv * 1024), 16, 0, 0); \
    } while (0)

__global__ __launch_bounds__(256, 2)
void gemm_i8(const signed char* __restrict__ Aq, const unsigned char* __restrict__ Bw4,
             const float* __restrict__ wscale, const float* __restrict__ wadd,
             const float* __restrict__ bias, const float* __restrict__ rowsum,
             const float* __restrict__ srow, float* __restrict__ out)
{
    __shared__ char smem[49152];

    const int tid  = threadIdx.x;
    const int lane = tid & 63;
    const int wv   = tid >> 6;    // wave 0..3 = output col quarter

    // XCD swizzle: 1024 wgs = 8 XCDs x 128
    const int bid = blockIdx.x;
    const int wg  = (bid & 7) * 128 + (bid >> 3);
    const int m0  = (wg >> 4) * 128;   // 64 m-tiles
    const int n0  = (wg & 15) * 256;   // 16 n-tiles

    // ---- A staging (verified pattern): round R = rows R*32..R*32+31 ----
    const int art = tid >> 3;
    const int act = (tid & 7) ^ (art & 7);
    const signed char* sA = Aq + (size_t)(m0 + art) * IN_DIM + act * 16;

    // ---- B staging: 64B rows, round R = rows R*64..R*64+63 ----
    const int brt = tid >> 2;
    const int bct = (tid & 3) ^ (brt & 3);
    const unsigned char* sB = Bw4 + (size_t)(n0 + brt) * 2048 + bct * 16;

    // ---- fragment read offsets ----
    const int l15 = lane & 15, g = lane >> 4, l7 = lane & 7, l3 = lane & 3;
    const int aOff = l15 * 128 + ((g ^ l7) << 4);
    const int bOff = 32768 + (wv * 64 + l15) * 64 + ((g ^ l3) << 4);

    i32x4 afr[4][2], b0[4], b1[4];
    i32x4 acc[8][4] = {};

    // ---- prologue ----
    STAGE_A(0, 0);
    STAGE_B(0);
    WAIT_VM(0);
    BAR();

    #pragma unroll 1
    for (int kt = 0; kt < NT; ++kt) {
        const int cur = kt & 1;

        STAGE_A(cur ^ 1, kt + 1);

        i32x4 bp[4];
        #pragma unroll
        for (int ni = 0; ni < 4; ++ni)
            bp[ni] = *(const i32x4*)(smem + bOff + ni * 1024);
        #pragma unroll
        for (int mi = 0; mi < 4; ++mi) {
            afr[mi][0] = *(const i32x4*)(smem + cur * 16384 + mi * 2048 + aOff);
            afr[mi][1] = *(const i32x4*)(smem + cur * 16384 + mi * 2048 + (aOff ^ 64));
        }
        #pragma unroll
        for (int ni = 0; ni < 4; ++ni) {
            #pragma unroll
            for (int d = 0; d < 4; ++d) {
                b0[ni][d] = bp[ni][d] & 0x0F0F0F0F;
                b1[ni][d] = (int)(((unsigned)bp[ni][d] >> 4) & 0x0F0F0F0F);
            }
        }

        WAIT_LGKM0();       // all own B reads complete before barrier
        BAR();              // all waves done reading B -> safe to restage
        STAGE_B(kt + 1);    // lands under the MFMA bursts below

        __builtin_amdgcn_s_setprio(1);
        #pragma unroll
        for (int mi = 0; mi < 4; ++mi)
            #pragma unroll
            for (int ni = 0; ni < 4; ++ni)
                acc[mi][ni] = __builtin_amdgcn_mfma_i32_16x16x64_i8(
                    afr[mi][0], b0[ni], acc[mi][ni], 0, 0, 0);
        #pragma unroll
        for (int mi = 0; mi < 4; ++mi)
            #pragma unroll
            for (int ni = 0; ni < 4; ++ni)
                acc[mi][ni] = __builtin_amdgcn_mfma_i32_16x16x64_i8(
                    afr[mi][1], b1[ni], acc[mi][ni], 0, 0, 0);
        __builtin_amdgcn_s_setprio(0);

        #pragma unroll
        for (int mi = 0; mi < 4; ++mi) {
            afr[mi][0] = *(const i32x4*)(smem + cur * 16384 + (mi + 4) * 2048 + aOff);
            afr[mi][1] = *(const i32x4*)(smem + cur * 16384 + (mi + 4) * 2048 + (aOff ^ 64));
        }
        __builtin_amdgcn_s_setprio(1);
        #pragma unroll
        for (int mi = 0; mi < 4; ++mi)
            #pragma unroll
            for (int ni = 0; ni < 4; ++ni)
                acc[mi + 4][ni] = __builtin_amdgcn_mfma_i32_16x16x64_i8(
                    afr[mi][0], b0[ni], acc[mi + 4][ni], 0, 0, 0);
        #pragma unroll
        for (int mi = 0; mi < 4; ++mi)
            #pragma unroll
            for (int ni = 0; ni < 4; ++ni)
                acc[mi + 4][ni] = __builtin_amdgcn_mfma_i32_16x16x64_i8(
                    afr[mi][1], b1[ni], acc[mi + 4][ni], 0, 0, 0);
        __builtin_amdgcn_s_setprio(0);

        WAIT_VM(0);         // A(kt+1)+B(kt+1) landed (issued a burst ago)
        BAR();
    }

    // ---- epilogue: y = srow[m]*wscale[n]*acc + wadd[n]*rowsum[m] + bias[n] ----
    #pragma unroll
    for (int ni = 0; ni < 4; ++ni) {
        const int col = n0 + wv * 64 + ni * 16 + l15;
        const float sc = wscale[col];
        const float ad = wadd[col];
        const float bi = bias[col];
        #pragma unroll
        for (int mi = 0; mi < 8; ++mi) {
            const int row = m0 + mi * 16 + g * 4;
            const float4 rs4 = *(const float4*)&rowsum[row];
            const float4 sr4 = *(const float4*)&srow[row];
            #pragma unroll
            for (int j = 0; j < 4; ++j) {
                const float rs = (j == 0) ? rs4.x : (j == 1) ? rs4.y : (j == 2) ? rs4.z : rs4.w;
                const float sr = (j == 0) ? sr4.x : (j == 1) ? sr4.y : (j == 2) ? sr4.z : sr4.w;
                out[(size_t)(row + j) * OUT_DIM + col] =
                    (float)acc[mi][ni][j] * (sc * sr) + ad * rs + bi;
            }
        }
    }
}

// ---------------------------------------------------------------------------
extern "C" void kernel_launch(void* const* d_in, const int* in_sizes, int n_in,
                              void* d_out, int out_size, void* d_ws, size_t ws_size,
                              hipStream_t stream)
{
    const float* x      = (const float*)d_in[0];
    const int*   wp     = (const int*)d_in[1];
    const float* wscale = (const float*)d_in[2];
    const float* wadd   = (const float*)d_in[3];
    const float* bias   = (const float*)d_in[4];
    float*       out    = (float*)d_out;

    const int M = in_sizes[0] / IN_DIM;   // 8192

    // ws layout: [ wf4 i4 N*K/2 (8MB) | aq i8 M*K | rowsum f32 M | srow f32 M ]
    char* ws = (char*)d_ws;
    unsigned char* wf4 = (unsigned char*)ws;
    const size_t wf_bytes = (size_t)OUT_DIM * IN_DIM / 2;
    int* aq = (int*)(ws + wf_bytes);
    const size_t aq_bytes = (size_t)M * IN_DIM;
    float* rowsum = (float*)(ws + wf_bytes + aq_bytes);
    float* srow   = (float*)(ws + wf_bytes + aq_bytes + (size_t)M * 4);

    unpack_w4i<<<(OUT_DIM * 32 * 4) / 256, 256, 0, stream>>>(wp, wf4);

    had_rows_q<<<M, 256, 0, stream>>>(x, aq, rowsum, srow);

    gemm_i8<<<(M / 128) * (OUT_DIM / 256), 256, 0, stream>>>(
        (const signed char*)aq, wf4, wscale, wadd, bias, rowsum, srow, out);
}

// Round 20
// 171.491 us; speedup vs baseline: 1.3880x; 1.0196x over previous
//
#include <hip/hip_runtime.h>
#include <hip/hip_bf16.h>
#include <hip/hip_fp16.h>

#define IN_DIM 4096
#define OUT_DIM 4096
#define HAD_SCALE_F 0.08838834764831845f   // 2^-3.5

typedef int   i32x4 __attribute__((ext_vector_type(4)));
typedef float f32x4 __attribute__((ext_vector_type(4)));

// ---------------------------------------------------------------------------
// Kernel A (verified R12/R13/R15): wave/in-register FWHT, 16 elems/thread,
// s_a = rowmax/127, rowsum = s_a*sum(q) (self-consistent decomposition).
// ---------------------------------------------------------------------------
__global__ __launch_bounds__(256)
void had_rows_q(const float* __restrict__ x, int* __restrict__ aq,
                float* __restrict__ rowsum, float* __restrict__ srow)
{
    __shared__ float wmx[4];
    __shared__ int   wqs[4];
    const int tid = threadIdx.x;
    const int wv  = tid >> 6;
    const size_t row = blockIdx.x;
    const float* xr = x + row * IN_DIM + tid * 16;

    float e[16];
    #pragma unroll
    for (int v = 0; v < 4; ++v) {
        const float4 f = ((const float4*)xr)[v];
        e[v*4+0] = f.x; e[v*4+1] = f.y; e[v*4+2] = f.z; e[v*4+3] = f.w;
    }

    #pragma unroll
    for (int s = 1; s < 16; s <<= 1) {
        #pragma unroll
        for (int i = 0; i < 16; ++i) {
            if (!(i & s)) {
                const float u = e[i], w2 = e[i | s];
                e[i]     = u + w2;
                e[i | s] = u - w2;
            }
        }
    }
    #pragma unroll
    for (int m = 1; m <= 4; m <<= 1) {
        const float sgn = (tid & m) ? -1.0f : 1.0f;
        #pragma unroll
        for (int i = 0; i < 16; ++i) {
            const float p = __shfl_xor(e[i], m, 64);
            e[i] = fmaf(sgn, e[i], p);
        }
    }

    float smax = 0.f;
    #pragma unroll
    for (int i = 0; i < 16; ++i) {
        e[i] *= HAD_SCALE_F;
        smax = fmaxf(smax, fabsf(e[i]));
    }
    #pragma unroll
    for (int off = 32; off > 0; off >>= 1)
        smax = fmaxf(smax, __shfl_xor(smax, off, 64));
    if ((tid & 63) == 0) wmx[wv] = smax;
    __syncthreads();
    const float mx  = fmaxf(fmaxf(wmx[0], wmx[1]), fmaxf(wmx[2], wmx[3]));
    const float inv = (mx > 0.f) ? 127.0f / mx : 0.f;
    const float sa  = mx * (1.0f / 127.0f);

    int qsum = 0;
    int pk[4];
    #pragma unroll
    for (int g2 = 0; g2 < 4; ++g2) {
        const int q0 = (int)rintf(e[g2*4+0] * inv);
        const int q1 = (int)rintf(e[g2*4+1] * inv);
        const int q2 = (int)rintf(e[g2*4+2] * inv);
        const int q3 = (int)rintf(e[g2*4+3] * inv);
        qsum += (q0 + q1) + (q2 + q3);
        pk[g2] = (q0 & 0xFF) | ((q1 & 0xFF) << 8) | ((q2 & 0xFF) << 16) | (q3 << 24);
    }
    *(int4*)&aq[row * (IN_DIM / 4) + tid * 4] = make_int4(pk[0], pk[1], pk[2], pk[3]);

    #pragma unroll
    for (int off = 32; off > 0; off >>= 1) qsum += __shfl_xor(qsum, off, 64);
    if ((tid & 63) == 0) wqs[wv] = qsum;
    __syncthreads();
    if (tid == 0) {
        rowsum[row] = sa * (float)((wqs[0] + wqs[1]) + (wqs[2] + wqs[3]));
        srow[row]   = sa;
    }
}

// ---------------------------------------------------------------------------
// Kernel B (verified R15): repack int4 weights into interleaved-nibble chunks.
// packed & 0x0F0F0F0F = kb0 fragment, (packed>>4) & 0x0F0F0F0F = kb1.
// ---------------------------------------------------------------------------
__global__ __launch_bounds__(256)
void unpack_w4i(const int* __restrict__ wp, unsigned char* __restrict__ wf4)
{
    const int gid = blockIdx.x * 256 + threadIdx.x;   // 4096*32*4 = 524288
    const int c   = gid & 3;
    const int kt  = (gid >> 2) & 31;
    const int n   = gid >> 7;
    const int kbase = kt * 128 + c * 16;
    const int* row = wp + (size_t)n * (IN_DIM / 2) + (kbase >> 1);
    const int4 plo0 = *(const int4*)(row);
    const int4 plo1 = *(const int4*)(row + 4);
    const int4 phi0 = *(const int4*)(row + 32);
    const int4 phi1 = *(const int4*)(row + 36);

    #define MKD(lo, hi, lo2, hi2) \
        ( (unsigned)(((lo) & 15) | (((hi) & 15) << 4)) \
        | ((unsigned)((((lo) >> 4) & 15) | ((((hi) >> 4) & 15) << 4)) << 8) \
        | ((unsigned)(((lo2) & 15) | (((hi2) & 15) << 4)) << 16) \
        | ((unsigned)((((lo2) >> 4) & 15) | ((((hi2) >> 4) & 15) << 4)) << 24) )

    uint4 o;
    o.x = MKD(plo0.x, phi0.x, plo0.y, phi0.y);
    o.y = MKD(plo0.z, phi0.z, plo0.w, phi0.w);
    o.z = MKD(plo1.x, phi1.x, plo1.y, phi1.y);
    o.w = MKD(plo1.z, phi1.z, plo1.w, phi1.w);
    #undef MKD
    *(uint4*)(wf4 + (size_t)gid * 16) = o;
}

// ---------------------------------------------------------------------------
// Kernel C (round-20): 128x256 block, 2x2 wave grid (wave tile 64x128),
// A AND B double-buffered (LDS 64 KiB -> still 2 blocks/CU).
// vs R15: (a) B dbuf removes the read-before-restage constraint -> ONE
// barrier per region, no mid-region lgkmcnt(0) drain (R15's sync term was
// ~33us beyond the additive floor); (b) 64x128 wave tile cuts LDS reads to
// 64 b128/block-region vs 80 (-20%): per wave A = 8 b128, B = 8 packed b128
// (each yields both kb halves). Same-region read->MFMA handled by compiler
// counted-lgkm + 8-wave/CU TLP. Ledger: buf[cur] reads consumed by MFMAs
// before the region-end barrier; restaged in kt+2 (>=1 barrier later).
// vmcnt(0) at region end drains stages issued a full region earlier.
// ---------------------------------------------------------------------------
#define NT 32   // K-regions of 128

#define BAR()        asm volatile("s_barrier" ::: "memory")
#define WAIT_VM(N)   asm volatile("s_waitcnt vmcnt(" #N ")" ::: "memory")

// LDS: A0 @ 0, A1 @ 16384, B0 @ 32768, B1 @ 49152 (each 16 KiB)
#define STAGE_A(buf, kt) do { \
    _Pragma("unroll") for (int R = 0; R < 4; ++R) \
        __builtin_amdgcn_global_load_lds( \
            (const __attribute__((address_space(1))) void*)(sA + ((size_t)R << 17) + (((kt) & 31) << 7)), \
            (__attribute__((address_space(3))) void*)(smem + (buf) * 16384 + R * 4096 + wv * 1024), 16, 0, 0); \
    } while (0)
#define STAGE_B(buf, kt) do { \
    _Pragma("unroll") for (int R = 0; R < 4; ++R) \
        __builtin_amdgcn_global_load_lds( \
            (const __attribute__((address_space(1))) void*)(sB + ((size_t)R << 17) + (((kt) & 31) << 6)), \
            (__attribute__((address_space(3))) void*)(smem + 32768 + (buf) * 16384 + R * 4096 + wv * 1024), 16, 0, 0); \
    } while (0)

__global__ __launch_bounds__(256, 2)
void gemm_i8(const signed char* __restrict__ Aq, const unsigned char* __restrict__ Bw4,
             const float* __restrict__ wscale, const float* __restrict__ wadd,
             const float* __restrict__ bias, const float* __restrict__ rowsum,
             const float* __restrict__ srow, float* __restrict__ out)
{
    __shared__ char smem[65536];

    const int tid  = threadIdx.x;
    const int lane = tid & 63;
    const int wv   = tid >> 6;    // wave 0..3
    const int wm   = wv >> 1;     // 2x2 wave grid: 64-row halves
    const int wn   = wv & 1;      // 128-col halves

    // XCD swizzle: 1024 wgs = 8 XCDs x 128
    const int bid = blockIdx.x;
    const int wg  = (bid & 7) * 128 + (bid >> 3);
    const int m0  = (wg >> 4) * 128;   // 64 m-tiles
    const int n0  = (wg & 15) * 256;   // 16 n-tiles

    // ---- A staging (verified pattern): round R = rows R*32..R*32+31 ----
    const int art = tid >> 3;
    const int act = (tid & 7) ^ (art & 7);
    const signed char* sA = Aq + (size_t)(m0 + art) * IN_DIM + act * 16;

    // ---- B staging (verified pattern): 64B rows, round R = rows R*64.. ----
    const int brt = tid >> 2;
    const int bct = (tid & 3) ^ (brt & 3);
    const unsigned char* sB = Bw4 + (size_t)(n0 + brt) * 2048 + bct * 16;

    // ---- fragment read offsets (verified swizzles) ----
    const int l15 = lane & 15, g = lane >> 4, l7 = lane & 7, l3 = lane & 3;
    const int aOff = (wm * 64 + l15) * 128 + ((g ^ l7) << 4);      // + mi*2048, ^64 kb1
    const int bOff = (wn * 128 + l15) * 64 + ((g ^ l3) << 4);      // + ni*1024

    i32x4 afr[4][2], b0[8], b1[8];
    i32x4 acc[4][8] = {};   // [mi 0..3][ni 0..7]

    // ---- prologue ----
    STAGE_A(0, 0);
    STAGE_B(0, 0);
    WAIT_VM(0);
    BAR();

    #pragma unroll 1
    for (int kt = 0; kt < NT; ++kt) {
        const int cur = kt & 1;

        // stage next region into the other buffers (drained at region end)
        STAGE_A(cur ^ 1, kt + 1);
        STAGE_B(cur ^ 1, kt + 1);

        // B reads in two halves to bound register liveness
        {
            i32x4 bp[4];
            #pragma unroll
            for (int ni = 0; ni < 4; ++ni)
                bp[ni] = *(const i32x4*)(smem + 32768 + cur * 16384 + bOff + ni * 1024);
            #pragma unroll
            for (int ni = 0; ni < 4; ++ni)
                #pragma unroll
                for (int d = 0; d < 4; ++d) {
                    b0[ni][d] = bp[ni][d] & 0x0F0F0F0F;
                    b1[ni][d] = (int)(((unsigned)bp[ni][d] >> 4) & 0x0F0F0F0F);
                }
        }
        {
            i32x4 bp[4];
            #pragma unroll
            for (int ni = 0; ni < 4; ++ni)
                bp[ni] = *(const i32x4*)(smem + 32768 + cur * 16384 + bOff + (ni + 4) * 1024);
            #pragma unroll
            for (int ni = 0; ni < 4; ++ni)
                #pragma unroll
                for (int d = 0; d < 4; ++d) {
                    b0[ni + 4][d] = bp[ni][d] & 0x0F0F0F0F;
                    b1[ni + 4][d] = (int)(((unsigned)bp[ni][d] >> 4) & 0x0F0F0F0F);
                }
        }
        #pragma unroll
        for (int mi = 0; mi < 4; ++mi) {
            afr[mi][0] = *(const i32x4*)(smem + cur * 16384 + mi * 2048 + aOff);
            afr[mi][1] = *(const i32x4*)(smem + cur * 16384 + mi * 2048 + (aOff ^ 64));
        }

        __builtin_amdgcn_s_setprio(1);
        #pragma unroll
        for (int mi = 0; mi < 4; ++mi)
            #pragma unroll
            for (int ni = 0; ni < 8; ++ni)
                acc[mi][ni] = __builtin_amdgcn_mfma_i32_16x16x64_i8(
                    afr[mi][0], b0[ni], acc[mi][ni], 0, 0, 0);
        #pragma unroll
        for (int mi = 0; mi < 4; ++mi)
            #pragma unroll
            for (int ni = 0; ni < 8; ++ni)
                acc[mi][ni] = __builtin_amdgcn_mfma_i32_16x16x64_i8(
                    afr[mi][1], b1[ni], acc[mi][ni], 0, 0, 0);
        __builtin_amdgcn_s_setprio(0);

        WAIT_VM(0);     // next-region stages landed (issued a full region ago)
        BAR();          // single barrier per region
    }

    // ---- epilogue: y = srow[m]*wscale[n]*acc + wadd[n]*rowsum[m] + bias[n] ----
    #pragma unroll
    for (int ni = 0; ni < 8; ++ni) {
        const int col = n0 + wn * 128 + ni * 16 + l15;
        const float sc = wscale[col];
        const float ad = wadd[col];
        const float bi = bias[col];
        #pragma unroll
        for (int mi = 0; mi < 4; ++mi) {
            const int row = m0 + wm * 64 + mi * 16 + g * 4;
            const float4 rs4 = *(const float4*)&rowsum[row];
            const float4 sr4 = *(const float4*)&srow[row];
            #pragma unroll
            for (int j = 0; j < 4; ++j) {
                const float rs = (j == 0) ? rs4.x : (j == 1) ? rs4.y : (j == 2) ? rs4.z : rs4.w;
                const float sr = (j == 0) ? sr4.x : (j == 1) ? sr4.y : (j == 2) ? sr4.z : sr4.w;
                out[(size_t)(row + j) * OUT_DIM + col] =
                    (float)acc[mi][ni][j] * (sc * sr) + ad * rs + bi;
            }
        }
    }
}

// ---------------------------------------------------------------------------
extern "C" void kernel_launch(void* const* d_in, const int* in_sizes, int n_in,
                              void* d_out, int out_size, void* d_ws, size_t ws_size,
                              hipStream_t stream)
{
    const float* x      = (const float*)d_in[0];
    const int*   wp     = (const int*)d_in[1];
    const float* wscale = (const float*)d_in[2];
    const float* wadd   = (const float*)d_in[3];
    const float* bias   = (const float*)d_in[4];
    float*       out    = (float*)d_out;

    const int M = in_sizes[0] / IN_DIM;   // 8192

    // ws layout: [ wf4 i4 N*K/2 (8MB) | aq i8 M*K | rowsum f32 M | srow f32 M ]
    char* ws = (char*)d_ws;
    unsigned char* wf4 = (unsigned char*)ws;
    const size_t wf_bytes = (size_t)OUT_DIM * IN_DIM / 2;
    int* aq = (int*)(ws + wf_bytes);
    const size_t aq_bytes = (size_t)M * IN_DIM;
    float* rowsum = (float*)(ws + wf_bytes + aq_bytes);
    float* srow   = (float*)(ws + wf_bytes + aq_bytes + (size_t)M * 4);

    unpack_w4i<<<(OUT_DIM * 32 * 4) / 256, 256, 0, stream>>>(wp, wf4);

    had_rows_q<<<M, 256, 0, stream>>>(x, aq, rowsum, srow);

    gemm_i8<<<(M / 128) * (OUT_DIM / 256), 256, 0, stream>>>(
        (const signed char*)aq, wf4, wscale, wadd, bias, rowsum, srow, out);
}

// Round 21
// 170.563 us; speedup vs baseline: 1.3955x; 1.0054x over previous
//
#include <hip/hip_runtime.h>
#include <hip/hip_bf16.h>
#include <hip/hip_fp16.h>

#define IN_DIM 4096
#define OUT_DIM 4096
#define HAD_SCALE_F 0.08838834764831845f   // 2^-3.5

typedef int   i32x4 __attribute__((ext_vector_type(4)));
typedef float f32x4 __attribute__((ext_vector_type(4)));

// ---------------------------------------------------------------------------
// Kernel A (verified R12/R13/R15): wave/in-register FWHT, 16 elems/thread,
// s_a = rowmax/127, rowsum = s_a*sum(q) (self-consistent decomposition).
// ---------------------------------------------------------------------------
__global__ __launch_bounds__(256)
void had_rows_q(const float* __restrict__ x, int* __restrict__ aq,
                float* __restrict__ rowsum, float* __restrict__ srow)
{
    __shared__ float wmx[4];
    __shared__ int   wqs[4];
    const int tid = threadIdx.x;
    const int wv  = tid >> 6;
    const size_t row = blockIdx.x;
    const float* xr = x + row * IN_DIM + tid * 16;

    float e[16];
    #pragma unroll
    for (int v = 0; v < 4; ++v) {
        const float4 f = ((const float4*)xr)[v];
        e[v*4+0] = f.x; e[v*4+1] = f.y; e[v*4+2] = f.z; e[v*4+3] = f.w;
    }

    #pragma unroll
    for (int s = 1; s < 16; s <<= 1) {
        #pragma unroll
        for (int i = 0; i < 16; ++i) {
            if (!(i & s)) {
                const float u = e[i], w2 = e[i | s];
                e[i]     = u + w2;
                e[i | s] = u - w2;
            }
        }
    }
    #pragma unroll
    for (int m = 1; m <= 4; m <<= 1) {
        const float sgn = (tid & m) ? -1.0f : 1.0f;
        #pragma unroll
        for (int i = 0; i < 16; ++i) {
            const float p = __shfl_xor(e[i], m, 64);
            e[i] = fmaf(sgn, e[i], p);
        }
    }

    float smax = 0.f;
    #pragma unroll
    for (int i = 0; i < 16; ++i) {
        e[i] *= HAD_SCALE_F;
        smax = fmaxf(smax, fabsf(e[i]));
    }
    #pragma unroll
    for (int off = 32; off > 0; off >>= 1)
        smax = fmaxf(smax, __shfl_xor(smax, off, 64));
    if ((tid & 63) == 0) wmx[wv] = smax;
    __syncthreads();
    const float mx  = fmaxf(fmaxf(wmx[0], wmx[1]), fmaxf(wmx[2], wmx[3]));
    const float inv = (mx > 0.f) ? 127.0f / mx : 0.f;
    const float sa  = mx * (1.0f / 127.0f);

    int qsum = 0;
    int pk[4];
    #pragma unroll
    for (int g2 = 0; g2 < 4; ++g2) {
        const int q0 = (int)rintf(e[g2*4+0] * inv);
        const int q1 = (int)rintf(e[g2*4+1] * inv);
        const int q2 = (int)rintf(e[g2*4+2] * inv);
        const int q3 = (int)rintf(e[g2*4+3] * inv);
        qsum += (q0 + q1) + (q2 + q3);
        pk[g2] = (q0 & 0xFF) | ((q1 & 0xFF) << 8) | ((q2 & 0xFF) << 16) | (q3 << 24);
    }
    *(int4*)&aq[row * (IN_DIM / 4) + tid * 4] = make_int4(pk[0], pk[1], pk[2], pk[3]);

    #pragma unroll
    for (int off = 32; off > 0; off >>= 1) qsum += __shfl_xor(qsum, off, 64);
    if ((tid & 63) == 0) wqs[wv] = qsum;
    __syncthreads();
    if (tid == 0) {
        rowsum[row] = sa * (float)((wqs[0] + wqs[1]) + (wqs[2] + wqs[3]));
        srow[row]   = sa;
    }
}

// ---------------------------------------------------------------------------
// Kernel B (verified R15): repack int4 weights into interleaved-nibble chunks.
// packed & 0x0F0F0F0F = kb0 fragment, (packed>>4) & 0x0F0F0F0F = kb1.
// ---------------------------------------------------------------------------
__global__ __launch_bounds__(256)
void unpack_w4i(const int* __restrict__ wp, unsigned char* __restrict__ wf4)
{
    const int gid = blockIdx.x * 256 + threadIdx.x;   // 4096*32*4 = 524288
    const int c   = gid & 3;
    const int kt  = (gid >> 2) & 31;
    const int n   = gid >> 7;
    const int kbase = kt * 128 + c * 16;
    const int* row = wp + (size_t)n * (IN_DIM / 2) + (kbase >> 1);
    const int4 plo0 = *(const int4*)(row);
    const int4 plo1 = *(const int4*)(row + 4);
    const int4 phi0 = *(const int4*)(row + 32);
    const int4 phi1 = *(const int4*)(row + 36);

    #define MKD(lo, hi, lo2, hi2) \
        ( (unsigned)(((lo) & 15) | (((hi) & 15) << 4)) \
        | ((unsigned)((((lo) >> 4) & 15) | ((((hi) >> 4) & 15) << 4)) << 8) \
        | ((unsigned)(((lo2) & 15) | (((hi2) & 15) << 4)) << 16) \
        | ((unsigned)((((lo2) >> 4) & 15) | ((((hi2) >> 4) & 15) << 4)) << 24) )

    uint4 o;
    o.x = MKD(plo0.x, phi0.x, plo0.y, phi0.y);
    o.y = MKD(plo0.z, phi0.z, plo0.w, phi0.w);
    o.z = MKD(plo1.x, phi1.x, plo1.y, phi1.y);
    o.w = MKD(plo1.z, phi1.z, plo1.w, phi1.w);
    #undef MKD
    *(uint4*)(wf4 + (size_t)gid * 16) = o;
}

// ---------------------------------------------------------------------------
// Kernel C (round-21): R20 winner + B bank-conflict fix. R20's B slot
// swizzle f(r)=r&3 had period 4 while the 64B-row bank pattern (16r mod 32)
// has period 2 -> rows r,r+4,r+8,r+12 hit the same slot+bank = 4-way
// conflict (4.19M cycles). New f(r)=(r>>1)&3 distributes the 8 rows that
// share a bank-half across all 4 slots -> exact 2-way aliasing (free,
// m136). Applied on BOTH sides (stage source bct and read bOff; round
// index drops out mod 4 since rounds are 64 rows). Everything else R20.
// ---------------------------------------------------------------------------
#define NT 32   // K-regions of 128

#define BAR()        asm volatile("s_barrier" ::: "memory")
#define WAIT_VM(N)   asm volatile("s_waitcnt vmcnt(" #N ")" ::: "memory")

// LDS: A0 @ 0, A1 @ 16384, B0 @ 32768, B1 @ 49152 (each 16 KiB)
#define STAGE_A(buf, kt) do { \
    _Pragma("unroll") for (int R = 0; R < 4; ++R) \
        __builtin_amdgcn_global_load_lds( \
            (const __attribute__((address_space(1))) void*)(sA + ((size_t)R << 17) + (((kt) & 31) << 7)), \
            (__attribute__((address_space(3))) void*)(smem + (buf) * 16384 + R * 4096 + wv * 1024), 16, 0, 0); \
    } while (0)
#define STAGE_B(buf, kt) do { \
    _Pragma("unroll") for (int R = 0; R < 4; ++R) \
        __builtin_amdgcn_global_load_lds( \
            (const __attribute__((address_space(1))) void*)(sB + ((size_t)R << 17) + (((kt) & 31) << 6)), \
            (__attribute__((address_space(3))) void*)(smem + 32768 + (buf) * 16384 + R * 4096 + wv * 1024), 16, 0, 0); \
    } while (0)

__global__ __launch_bounds__(256, 2)
void gemm_i8(const signed char* __restrict__ Aq, const unsigned char* __restrict__ Bw4,
             const float* __restrict__ wscale, const float* __restrict__ wadd,
             const float* __restrict__ bias, const float* __restrict__ rowsum,
             const float* __restrict__ srow, float* __restrict__ out)
{
    __shared__ char smem[65536];

    const int tid  = threadIdx.x;
    const int lane = tid & 63;
    const int wv   = tid >> 6;    // wave 0..3
    const int wm   = wv >> 1;     // 2x2 wave grid: 64-row halves
    const int wn   = wv & 1;      // 128-col halves

    // XCD swizzle: 1024 wgs = 8 XCDs x 128
    const int bid = blockIdx.x;
    const int wg  = (bid & 7) * 128 + (bid >> 3);
    const int m0  = (wg >> 4) * 128;   // 64 m-tiles
    const int n0  = (wg & 15) * 256;   // 16 n-tiles

    // ---- A staging (verified pattern): round R = rows R*32..R*32+31 ----
    const int art = tid >> 3;
    const int act = (tid & 7) ^ (art & 7);
    const signed char* sA = Aq + (size_t)(m0 + art) * IN_DIM + act * 16;

    // ---- B staging: 64B rows, round R = rows R*64..; slot f(r)=(r>>1)&3 ----
    const int brt = tid >> 2;
    const int bct = (tid & 3) ^ ((brt >> 1) & 3);
    const unsigned char* sB = Bw4 + (size_t)(n0 + brt) * 2048 + bct * 16;

    // ---- fragment read offsets ----
    const int l15 = lane & 15, g = lane >> 4, l7 = lane & 7;
    const int aOff = (wm * 64 + l15) * 128 + ((g ^ l7) << 4);           // + mi*2048, ^64 kb1
    const int bOff = (wn * 128 + l15) * 64 + ((g ^ ((l15 >> 1) & 3)) << 4);  // + ni*1024

    i32x4 afr[4][2], b0[8], b1[8];
    i32x4 acc[4][8] = {};   // [mi 0..3][ni 0..7]

    // ---- prologue ----
    STAGE_A(0, 0);
    STAGE_B(0, 0);
    WAIT_VM(0);
    BAR();

    #pragma unroll 1
    for (int kt = 0; kt < NT; ++kt) {
        const int cur = kt & 1;

        // stage next region into the other buffers (drained at region end)
        STAGE_A(cur ^ 1, kt + 1);
        STAGE_B(cur ^ 1, kt + 1);

        // B reads in two halves to bound register liveness
        {
            i32x4 bp[4];
            #pragma unroll
            for (int ni = 0; ni < 4; ++ni)
                bp[ni] = *(const i32x4*)(smem + 32768 + cur * 16384 + bOff + ni * 1024);
            #pragma unroll
            for (int ni = 0; ni < 4; ++ni)
                #pragma unroll
                for (int d = 0; d < 4; ++d) {
                    b0[ni][d] = bp[ni][d] & 0x0F0F0F0F;
                    b1[ni][d] = (int)(((unsigned)bp[ni][d] >> 4) & 0x0F0F0F0F);
                }
        }
        {
            i32x4 bp[4];
            #pragma unroll
            for (int ni = 0; ni < 4; ++ni)
                bp[ni] = *(const i32x4*)(smem + 32768 + cur * 16384 + bOff + (ni + 4) * 1024);
            #pragma unroll
            for (int ni = 0; ni < 4; ++ni)
                #pragma unroll
                for (int d = 0; d < 4; ++d) {
                    b0[ni + 4][d] = bp[ni][d] & 0x0F0F0F0F;
                    b1[ni + 4][d] = (int)(((unsigned)bp[ni][d] >> 4) & 0x0F0F0F0F);
                }
        }
        #pragma unroll
        for (int mi = 0; mi < 4; ++mi) {
            afr[mi][0] = *(const i32x4*)(smem + cur * 16384 + mi * 2048 + aOff);
            afr[mi][1] = *(const i32x4*)(smem + cur * 16384 + mi * 2048 + (aOff ^ 64));
        }

        __builtin_amdgcn_s_setprio(1);
        #pragma unroll
        for (int mi = 0; mi < 4; ++mi)
            #pragma unroll
            for (int ni = 0; ni < 8; ++ni)
                acc[mi][ni] = __builtin_amdgcn_mfma_i32_16x16x64_i8(
                    afr[mi][0], b0[ni], acc[mi][ni], 0, 0, 0);
        #pragma unroll
        for (int mi = 0; mi < 4; ++mi)
            #pragma unroll
            for (int ni = 0; ni < 8; ++ni)
                acc[mi][ni] = __builtin_amdgcn_mfma_i32_16x16x64_i8(
                    afr[mi][1], b1[ni], acc[mi][ni], 0, 0, 0);
        __builtin_amdgcn_s_setprio(0);

        WAIT_VM(0);     // next-region stages landed (issued a full region ago)
        BAR();          // single barrier per region
    }

    // ---- epilogue: y = srow[m]*wscale[n]*acc + wadd[n]*rowsum[m] + bias[n] ----
    #pragma unroll
    for (int ni = 0; ni < 8; ++ni) {
        const int col = n0 + wn * 128 + ni * 16 + l15;
        const float sc = wscale[col];
        const float ad = wadd[col];
        const float bi = bias[col];
        #pragma unroll
        for (int mi = 0; mi < 4; ++mi) {
            const int row = m0 + wm * 64 + mi * 16 + g * 4;
            const float4 rs4 = *(const float4*)&rowsum[row];
            const float4 sr4 = *(const float4*)&srow[row];
            #pragma unroll
            for (int j = 0; j < 4; ++j) {
                const float rs = (j == 0) ? rs4.x : (j == 1) ? rs4.y : (j == 2) ? rs4.z : rs4.w;
                const float sr = (j == 0) ? sr4.x : (j == 1) ? sr4.y : (j == 2) ? sr4.z : sr4.w;
                out[(size_t)(row + j) * OUT_DIM + col] =
                    (float)acc[mi][ni][j] * (sc * sr) + ad * rs + bi;
            }
        }
    }
}

// ---------------------------------------------------------------------------
extern "C" void kernel_launch(void* const* d_in, const int* in_sizes, int n_in,
                              void* d_out, int out_size, void* d_ws, size_t ws_size,
                              hipStream_t stream)
{
    const float* x      = (const float*)d_in[0];
    const int*   wp     = (const int*)d_in[1];
    const float* wscale = (const float*)d_in[2];
    const float* wadd   = (const float*)d_in[3];
    const float* bias   = (const float*)d_in[4];
    float*       out    = (float*)d_out;

    const int M = in_sizes[0] / IN_DIM;   // 8192

    // ws layout: [ wf4 i4 N*K/2 (8MB) | aq i8 M*K | rowsum f32 M | srow f32 M ]
    char* ws = (char*)d_ws;
    unsigned char* wf4 = (unsigned char*)ws;
    const size_t wf_bytes = (size_t)OUT_DIM * IN_DIM / 2;
    int* aq = (int*)(ws + wf_bytes);
    const size_t aq_bytes = (size_t)M * IN_DIM;
    float* rowsum = (float*)(ws + wf_bytes + aq_bytes);
    float* srow   = (float*)(ws + wf_bytes + aq_bytes + (size_t)M * 4);

    unpack_w4i<<<(OUT_DIM * 32 * 4) / 256, 256, 0, stream>>>(wp, wf4);

    had_rows_q<<<M, 256, 0, stream>>>(x, aq, rowsum, srow);

    gemm_i8<<<(M / 128) * (OUT_DIM / 256), 256, 0, stream>>>(
        (const signed char*)aq, wf4, wscale, wadd, bias, rowsum, srow, out);
}

// Round 22
// 166.523 us; speedup vs baseline: 1.4294x; 1.0243x over previous
//
#include <hip/hip_runtime.h>
#include <hip/hip_bf16.h>
#include <hip/hip_fp16.h>

#define IN_DIM 4096
#define OUT_DIM 4096
#define HAD_SCALE_F 0.08838834764831845f   // 2^-3.5

typedef int   i32x4 __attribute__((ext_vector_type(4)));
typedef float f32x4 __attribute__((ext_vector_type(4)));

// ---------------------------------------------------------------------------
// Kernel P (round-22): MERGED prep. Blocks [0, M): per-row FWHT + int8
// quantization (verified R12/R13 body). Blocks [M, M+2048): int4 weight
// repack (verified R15 body). The two workloads are independent; merging
// overlaps the 6.5us unpack under the 28us row pass and saves a launch.
// ---------------------------------------------------------------------------
__global__ __launch_bounds__(256)
void prep(const float* __restrict__ x, const int* __restrict__ wp,
          int* __restrict__ aq, unsigned char* __restrict__ wf4,
          float* __restrict__ rowsum, float* __restrict__ srow, int M)
{
    const int tid = threadIdx.x;

    if ((int)blockIdx.x >= M) {
        // ---- weight repack: interleaved-nibble chunks ----
        const int gid = ((int)blockIdx.x - M) * 256 + tid;   // 524288 total
        const int c   = gid & 3;
        const int kt  = (gid >> 2) & 31;
        const int n   = gid >> 7;
        const int kbase = kt * 128 + c * 16;
        const int* row = wp + (size_t)n * (IN_DIM / 2) + (kbase >> 1);
        const int4 plo0 = *(const int4*)(row);
        const int4 plo1 = *(const int4*)(row + 4);
        const int4 phi0 = *(const int4*)(row + 32);
        const int4 phi1 = *(const int4*)(row + 36);

        #define MKD(lo, hi, lo2, hi2) \
            ( (unsigned)(((lo) & 15) | (((hi) & 15) << 4)) \
            | ((unsigned)((((lo) >> 4) & 15) | ((((hi) >> 4) & 15) << 4)) << 8) \
            | ((unsigned)(((lo2) & 15) | (((hi2) & 15) << 4)) << 16) \
            | ((unsigned)((((lo2) >> 4) & 15) | ((((hi2) >> 4) & 15) << 4)) << 24) )

        uint4 o;
        o.x = MKD(plo0.x, phi0.x, plo0.y, phi0.y);
        o.y = MKD(plo0.z, phi0.z, plo0.w, phi0.w);
        o.z = MKD(plo1.x, phi1.x, plo1.y, phi1.y);
        o.w = MKD(plo1.z, phi1.z, plo1.w, phi1.w);
        #undef MKD
        *(uint4*)(wf4 + (size_t)gid * 16) = o;
        return;
    }

    // ---- row FWHT + quantization ----
    __shared__ float wmx[4];
    __shared__ int   wqs[4];
    const int wv  = tid >> 6;
    const size_t row = blockIdx.x;
    const float* xr = x + row * IN_DIM + tid * 16;

    float e[16];
    #pragma unroll
    for (int v = 0; v < 4; ++v) {
        const float4 f = ((const float4*)xr)[v];
        e[v*4+0] = f.x; e[v*4+1] = f.y; e[v*4+2] = f.z; e[v*4+3] = f.w;
    }

    #pragma unroll
    for (int s = 1; s < 16; s <<= 1) {
        #pragma unroll
        for (int i = 0; i < 16; ++i) {
            if (!(i & s)) {
                const float u = e[i], w2 = e[i | s];
                e[i]     = u + w2;
                e[i | s] = u - w2;
            }
        }
    }
    #pragma unroll
    for (int m = 1; m <= 4; m <<= 1) {
        const float sgn = (tid & m) ? -1.0f : 1.0f;
        #pragma unroll
        for (int i = 0; i < 16; ++i) {
            const float p = __shfl_xor(e[i], m, 64);
            e[i] = fmaf(sgn, e[i], p);
        }
    }

    float smax = 0.f;
    #pragma unroll
    for (int i = 0; i < 16; ++i) {
        e[i] *= HAD_SCALE_F;
        smax = fmaxf(smax, fabsf(e[i]));
    }
    #pragma unroll
    for (int off = 32; off > 0; off >>= 1)
        smax = fmaxf(smax, __shfl_xor(smax, off, 64));
    if ((tid & 63) == 0) wmx[wv] = smax;
    __syncthreads();
    const float mx  = fmaxf(fmaxf(wmx[0], wmx[1]), fmaxf(wmx[2], wmx[3]));
    const float inv = (mx > 0.f) ? 127.0f / mx : 0.f;
    const float sa  = mx * (1.0f / 127.0f);

    int qsum = 0;
    int pk[4];
    #pragma unroll
    for (int g2 = 0; g2 < 4; ++g2) {
        const int q0 = (int)rintf(e[g2*4+0] * inv);
        const int q1 = (int)rintf(e[g2*4+1] * inv);
        const int q2 = (int)rintf(e[g2*4+2] * inv);
        const int q3 = (int)rintf(e[g2*4+3] * inv);
        qsum += (q0 + q1) + (q2 + q3);
        pk[g2] = (q0 & 0xFF) | ((q1 & 0xFF) << 8) | ((q2 & 0xFF) << 16) | (q3 << 24);
    }
    *(int4*)&aq[row * (IN_DIM / 4) + tid * 4] = make_int4(pk[0], pk[1], pk[2], pk[3]);

    #pragma unroll
    for (int off = 32; off > 0; off >>= 1) qsum += __shfl_xor(qsum, off, 64);
    if ((tid & 63) == 0) wqs[wv] = qsum;
    __syncthreads();
    if (tid == 0) {
        rowsum[row] = sa * (float)((wqs[0] + wqs[1]) + (wqs[2] + wqs[3]));
        srow[row]   = sa;
    }
}

// ---------------------------------------------------------------------------
// Kernel C (verified R21, best): 128x256 block, 2x2 wave grid (64x128 wave
// tile), A+B double-buffered (64 KiB LDS, 2 blocks/CU), packed-int4 B with
// in-register nibble unpack, single barrier/region, 0 bank conflicts
// (A slot f(r)=r&7 on 128B rows; B slot f(r)=(r>>1)&3 on 64B rows).
// 125.7us, MfmaUtil 50.6 — additive cycle model closes within 1%.
// ---------------------------------------------------------------------------
#define NT 32   // K-regions of 128

#define BAR()        asm volatile("s_barrier" ::: "memory")
#define WAIT_VM(N)   asm volatile("s_waitcnt vmcnt(" #N ")" ::: "memory")

// LDS: A0 @ 0, A1 @ 16384, B0 @ 32768, B1 @ 49152 (each 16 KiB)
#define STAGE_A(buf, kt) do { \
    _Pragma("unroll") for (int R = 0; R < 4; ++R) \
        __builtin_amdgcn_global_load_lds( \
            (const __attribute__((address_space(1))) void*)(sA + ((size_t)R << 17) + (((kt) & 31) << 7)), \
            (__attribute__((address_space(3))) void*)(smem + (buf) * 16384 + R * 4096 + wv * 1024), 16, 0, 0); \
    } while (0)
#define STAGE_B(buf, kt) do { \
    _Pragma("unroll") for (int R = 0; R < 4; ++R) \
        __builtin_amdgcn_global_load_lds( \
            (const __attribute__((address_space(1))) void*)(sB + ((size_t)R << 17) + (((kt) & 31) << 6)), \
            (__attribute__((address_space(3))) void*)(smem + 32768 + (buf) * 16384 + R * 4096 + wv * 1024), 16, 0, 0); \
    } while (0)

__global__ __launch_bounds__(256, 2)
void gemm_i8(const signed char* __restrict__ Aq, const unsigned char* __restrict__ Bw4,
             const float* __restrict__ wscale, const float* __restrict__ wadd,
             const float* __restrict__ bias, const float* __restrict__ rowsum,
             const float* __restrict__ srow, float* __restrict__ out)
{
    __shared__ char smem[65536];

    const int tid  = threadIdx.x;
    const int lane = tid & 63;
    const int wv   = tid >> 6;    // wave 0..3
    const int wm   = wv >> 1;     // 2x2 wave grid: 64-row halves
    const int wn   = wv & 1;      // 128-col halves

    // XCD swizzle: 1024 wgs = 8 XCDs x 128
    const int bid = blockIdx.x;
    const int wg  = (bid & 7) * 128 + (bid >> 3);
    const int m0  = (wg >> 4) * 128;   // 64 m-tiles
    const int n0  = (wg & 15) * 256;   // 16 n-tiles

    // ---- A staging: round R = rows R*32..R*32+31, slot f(r)=r&7 ----
    const int art = tid >> 3;
    const int act = (tid & 7) ^ (art & 7);
    const signed char* sA = Aq + (size_t)(m0 + art) * IN_DIM + act * 16;

    // ---- B staging: 64B rows, round R = rows R*64..; slot f(r)=(r>>1)&3 ----
    const int brt = tid >> 2;
    const int bct = (tid & 3) ^ ((brt >> 1) & 3);
    const unsigned char* sB = Bw4 + (size_t)(n0 + brt) * 2048 + bct * 16;

    // ---- fragment read offsets ----
    const int l15 = lane & 15, g = lane >> 4, l7 = lane & 7;
    const int aOff = (wm * 64 + l15) * 128 + ((g ^ l7) << 4);           // + mi*2048, ^64 kb1
    const int bOff = (wn * 128 + l15) * 64 + ((g ^ ((l15 >> 1) & 3)) << 4);  // + ni*1024

    i32x4 afr[4][2], b0[8], b1[8];
    i32x4 acc[4][8] = {};   // [mi 0..3][ni 0..7]

    // ---- prologue ----
    STAGE_A(0, 0);
    STAGE_B(0, 0);
    WAIT_VM(0);
    BAR();

    #pragma unroll 1
    for (int kt = 0; kt < NT; ++kt) {
        const int cur = kt & 1;

        // stage next region into the other buffers (drained at region end)
        STAGE_A(cur ^ 1, kt + 1);
        STAGE_B(cur ^ 1, kt + 1);

        // B reads in two halves to bound register liveness
        {
            i32x4 bp[4];
            #pragma unroll
            for (int ni = 0; ni < 4; ++ni)
                bp[ni] = *(const i32x4*)(smem + 32768 + cur * 16384 + bOff + ni * 1024);
            #pragma unroll
            for (int ni = 0; ni < 4; ++ni)
                #pragma unroll
                for (int d = 0; d < 4; ++d) {
                    b0[ni][d] = bp[ni][d] & 0x0F0F0F0F;
                    b1[ni][d] = (int)(((unsigned)bp[ni][d] >> 4) & 0x0F0F0F0F);
                }
        }
        {
            i32x4 bp[4];
            #pragma unroll
            for (int ni = 0; ni < 4; ++ni)
                bp[ni] = *(const i32x4*)(smem + 32768 + cur * 16384 + bOff + (ni + 4) * 1024);
            #pragma unroll
            for (int ni = 0; ni < 4; ++ni)
                #pragma unroll
                for (int d = 0; d < 4; ++d) {
                    b0[ni + 4][d] = bp[ni][d] & 0x0F0F0F0F;
                    b1[ni + 4][d] = (int)(((unsigned)bp[ni][d] >> 4) & 0x0F0F0F0F);
                }
        }
        #pragma unroll
        for (int mi = 0; mi < 4; ++mi) {
            afr[mi][0] = *(const i32x4*)(smem + cur * 16384 + mi * 2048 + aOff);
            afr[mi][1] = *(const i32x4*)(smem + cur * 16384 + mi * 2048 + (aOff ^ 64));
        }

        __builtin_amdgcn_s_setprio(1);
        #pragma unroll
        for (int mi = 0; mi < 4; ++mi)
            #pragma unroll
            for (int ni = 0; ni < 8; ++ni)
                acc[mi][ni] = __builtin_amdgcn_mfma_i32_16x16x64_i8(
                    afr[mi][0], b0[ni], acc[mi][ni], 0, 0, 0);
        #pragma unroll
        for (int mi = 0; mi < 4; ++mi)
            #pragma unroll
            for (int ni = 0; ni < 8; ++ni)
                acc[mi][ni] = __builtin_amdgcn_mfma_i32_16x16x64_i8(
                    afr[mi][1], b1[ni], acc[mi][ni], 0, 0, 0);
        __builtin_amdgcn_s_setprio(0);

        WAIT_VM(0);     // next-region stages landed (issued a full region ago)
        BAR();          // single barrier per region
    }

    // ---- epilogue: y = srow[m]*wscale[n]*acc + wadd[n]*rowsum[m] + bias[n] ----
    #pragma unroll
    for (int ni = 0; ni < 8; ++ni) {
        const int col = n0 + wn * 128 + ni * 16 + l15;
        const float sc = wscale[col];
        const float ad = wadd[col];
        const float bi = bias[col];
        #pragma unroll
        for (int mi = 0; mi < 4; ++mi) {
            const int row = m0 + wm * 64 + mi * 16 + g * 4;
            const float4 rs4 = *(const float4*)&rowsum[row];
            const float4 sr4 = *(const float4*)&srow[row];
            #pragma unroll
            for (int j = 0; j < 4; ++j) {
                const float rs = (j == 0) ? rs4.x : (j == 1) ? rs4.y : (j == 2) ? rs4.z : rs4.w;
                const float sr = (j == 0) ? sr4.x : (j == 1) ? sr4.y : (j == 2) ? sr4.z : sr4.w;
                out[(size_t)(row + j) * OUT_DIM + col] =
                    (float)acc[mi][ni][j] * (sc * sr) + ad * rs + bi;
            }
        }
    }
}

// ---------------------------------------------------------------------------
extern "C" void kernel_launch(void* const* d_in, const int* in_sizes, int n_in,
                              void* d_out, int out_size, void* d_ws, size_t ws_size,
                              hipStream_t stream)
{
    const float* x      = (const float*)d_in[0];
    const int*   wp     = (const int*)d_in[1];
    const float* wscale = (const float*)d_in[2];
    const float* wadd   = (const float*)d_in[3];
    const float* bias   = (const float*)d_in[4];
    float*       out    = (float*)d_out;

    const int M = in_sizes[0] / IN_DIM;   // 8192

    // ws layout: [ wf4 i4 N*K/2 (8MB) | aq i8 M*K | rowsum f32 M | srow f32 M ]
    char* ws = (char*)d_ws;
    unsigned char* wf4 = (unsigned char*)ws;
    const size_t wf_bytes = (size_t)OUT_DIM * IN_DIM / 2;
    int* aq = (int*)(ws + wf_bytes);
    const size_t aq_bytes = (size_t)M * IN_DIM;
    float* rowsum = (float*)(ws + wf_bytes + aq_bytes);
    float* srow   = (float*)(ws + wf_bytes + aq_bytes + (size_t)M * 4);

    const int unpack_blocks = (OUT_DIM * 32 * 4) / 256;   // 2048
    prep<<<M + unpack_blocks, 256, 0, stream>>>(x, wp, aq, wf4, rowsum, srow, M);

    gemm_i8<<<(M / 128) * (OUT_DIM / 256), 256, 0, stream>>>(
        (const signed char*)aq, wf4, wscale, wadd, bias, rowsum, srow, out);
}